// Round 6
// baseline (150.721 us; speedup 1.0000x reference)
//
#include <hip/hip_runtime.h>

#define B 256
#define EPSV 1e-5f

// ---------- output offsets (f32 elements) ----------
#define OFF_ASSIGN 0
#define OFF_LOSS   256
#define OFF_ACT4   257
#define OFF_L1     2817
#define OFF_L2     12847873
#define OFF_L3     14486273

__device__ inline void wave_reduce2(float& s, float& q) {
#pragma unroll
    for (int o = 32; o > 0; o >>= 1) {
        s += __shfl_down(s, o, 64);
        q += __shfl_down(q, o, 64);
    }
}

// conv1: [B,3,32,32] -> raw c1 [B,6,28,28] + per-(b,c) sum/sumsq partials
__global__ __launch_bounds__(256) void conv1_kernel(
        const float* __restrict__ inp, const float* __restrict__ w,
        const float* __restrict__ bias, float* __restrict__ c1,
        float* __restrict__ part) {
    int bc = blockIdx.x; int b = bc / 6, c = bc % 6;
    int tid = threadIdx.x;
    __shared__ float ws[75];
    __shared__ float rs[4], rq[4];
    if (tid < 75) ws[tid] = w[c * 75 + tid];
    __syncthreads();
    const float* ip = inp + b * 3072;
    float bs = bias[c];
    float s = 0.f, sq = 0.f;
    for (int hw = tid; hw < 784; hw += 256) {
        int oh = hw / 28, ow = hw % 28;
        float acc = bs;
#pragma unroll
        for (int ic = 0; ic < 3; ++ic) {
            const float* ipc = ip + ic * 1024 + oh * 32 + ow;
            const float* wc = ws + ic * 25;
#pragma unroll
            for (int kh = 0; kh < 5; ++kh)
#pragma unroll
                for (int kw = 0; kw < 5; ++kw)
                    acc += ipc[kh * 32 + kw] * wc[kh * 5 + kw];
        }
        c1[bc * 784 + hw] = acc;
        s += acc; sq += acc * acc;
    }
    wave_reduce2(s, sq);
    if ((tid & 63) == 0) { rs[tid >> 6] = s; rq[tid >> 6] = sq; }
    __syncthreads();
    if (tid == 0) {
        part[bc * 2]     = rs[0] + rs[1] + rs[2] + rs[3];
        part[bc * 2 + 1] = rq[0] + rq[1] + rq[2] + rq[3];
    }
}

// per-channel stats from B partials; grid = C blocks, 256 thr (one per b)
__global__ void stats_kernel(const float* __restrict__ part, float* __restrict__ stats,
                             int C, float invN) {
    int c = blockIdx.x, tid = threadIdx.x;
    float s = part[(tid * C + c) * 2];
    float q = part[(tid * C + c) * 2 + 1];
    wave_reduce2(s, q);
    __shared__ float rs[4], rq[4];
    if ((tid & 63) == 0) { rs[tid >> 6] = s; rq[tid >> 6] = q; }
    __syncthreads();
    if (tid == 0) {
        float S = rs[0] + rs[1] + rs[2] + rs[3];
        float Q = rq[0] + rq[1] + rq[2] + rq[3];
        float m = S * invN;
        float v = Q * invN - m * m;
        stats[c] = m; stats[C + c] = v;
    }
}

// logits1 (+fused BN-relu-pool -> x1 in 1-of-49 blocks)
__global__ __launch_bounds__(256) void logits1_kernel(
        const float* __restrict__ c1, const float* __restrict__ st,
        const float* __restrict__ g, const float* __restrict__ bb,
        const float* __restrict__ k1s, float* __restrict__ outL1,
        float* __restrict__ x1) {
    __shared__ float sk[384];
    __shared__ float ssc[6], ssh[6];
    int tid = threadIdx.x;
    if (tid < 6) {
        float m = st[tid], v = st[6 + tid];
        float sc = g[tid] * rsqrtf(v + EPSV);
        ssc[tid] = sc; ssh[tid] = bb[tid] - m * sc;
    }
    for (int i = tid; i < 384; i += 256) sk[i] = k1s[i];
    __syncthreads();
    int t = blockIdx.x * 256 + tid;          // B*16*784 = 3211264
    int hw = t % 784; int u = t / 784; int kq = u & 15; int b = u >> 4;
    float a[6];
#pragma unroll
    for (int c = 0; c < 6; ++c)
        a[c] = c1[(b * 6 + c) * 784 + hw] * ssc[c] + ssh[c];
    float* op = outL1 + (long)b * 50176 + kq * 3136 + hw;
#pragma unroll
    for (int j = 0; j < 4; ++j) {
        int k = kq * 4 + j;
        float s = 0.f;
#pragma unroll
        for (int c = 0; c < 6; ++c) { float d = a[c] - sk[k * 6 + c]; s += d * d; }
        op[j * 784] = -sqrtf(s);
    }
    // fused BN+relu+pool: first block of each batch writes x1[b]
    if ((blockIdx.x % 49) == 0) {
        int bb2 = blockIdx.x / 49;
        const float* cp = c1 + bb2 * 4704;
        for (int i = tid; i < 1176; i += 256) {
            int c = i / 196, p = i % 196, ph = p / 14, pw = p % 14;
            const float* ap = cp + c * 784 + ph * 56 + pw * 2;
            float sc = ssc[c], sh = ssh[c];
            float v0 = ap[0] * sc + sh, v1 = ap[1] * sc + sh;
            float v2 = ap[28] * sc + sh, v3 = ap[29] * sc + sh;
            x1[bb2 * 1176 + i] = fmaxf(fmaxf(fmaxf(v0, v1), fmaxf(v2, v3)), 0.f);
        }
    }
}

// conv2: x1 [B,6,14,14] -> raw c2 [B,16,10,10] + partials; block=(b,c), 128 thr
__global__ __launch_bounds__(128) void conv2_kernel(
        const float* __restrict__ x1, const float* __restrict__ w,
        const float* __restrict__ bias, float* __restrict__ c2,
        float* __restrict__ part) {
    int bc = blockIdx.x; int b = bc >> 4, c = bc & 15;
    int tid = threadIdx.x;  // 128
    __shared__ float xs[1176];
    __shared__ float ws[150];
    __shared__ float rs[2], rq[2];
    for (int i = tid; i < 1176; i += 128) xs[i] = x1[b * 1176 + i];
    for (int i = tid; i < 150; i += 128) ws[i] = w[c * 150 + i];
    __syncthreads();
    float val = 0.f;
    if (tid < 100) {
        int oh = tid / 10, ow = tid % 10;
        float acc = bias[c];
#pragma unroll
        for (int ic = 0; ic < 6; ++ic) {
            const float* xp = xs + ic * 196 + oh * 14 + ow;
            const float* wp = ws + ic * 25;
#pragma unroll
            for (int kh = 0; kh < 5; ++kh)
#pragma unroll
                for (int kw = 0; kw < 5; ++kw)
                    acc += xp[kh * 14 + kw] * wp[kh * 5 + kw];
        }
        c2[bc * 100 + tid] = acc;
        val = acc;
    }
    float s = val, sq = val * val;
    wave_reduce2(s, sq);
    if ((tid & 63) == 0) { rs[tid >> 6] = s; rq[tid >> 6] = sq; }
    __syncthreads();
    if (tid == 0) {
        part[bc * 2]     = rs[0] + rs[1];
        part[bc * 2 + 1] = rq[0] + rq[1];
    }
}

// logits2 (+fused pool -> x2 in 1-of-25 blocks); act2 staged BN'd in LDS
__global__ __launch_bounds__(256) void logits2_kernel(
        const float* __restrict__ c2, const float* __restrict__ st,
        const float* __restrict__ g, const float* __restrict__ bb,
        const float* __restrict__ k2s, float* __restrict__ outL2,
        float* __restrict__ x2) {
    __shared__ float sk[1024];
    __shared__ float sa[1600];
    __shared__ float ssc[16], ssh[16];
    int tid = threadIdx.x;
    int t0 = blockIdx.x * 256;
    int b = t0 / 6400;                       // constant per block (6400 % 256 == 0)
    if (tid < 16) {
        float m = st[tid], v = st[16 + tid];
        float sc = g[tid] * rsqrtf(v + EPSV);
        ssc[tid] = sc; ssh[tid] = bb[tid] - m * sc;
    }
    for (int i = tid; i < 1024; i += 256) sk[i] = k2s[i];
    __syncthreads();
    for (int i = tid; i < 1600; i += 256) {
        int c = i / 100;
        sa[i] = c2[b * 1600 + i] * ssc[c] + ssh[c];
    }
    __syncthreads();
    int t = t0 + tid;
    int hw = t % 100; int k = (t / 100) & 63;
    float s = 0.f;
#pragma unroll
    for (int c = 0; c < 16; ++c) { float d = sa[c * 100 + hw] - sk[k * 16 + c]; s += d * d; }
    outL2[t] = -sqrtf(s);
    if ((blockIdx.x % 25) == 0) {            // fused relu+pool from BN'd LDS tile
        for (int i = tid; i < 400; i += 256) {
            int c = i / 25, p = i % 25, ph = p / 5, pw = p % 5;
            const float* ap = sa + c * 100 + ph * 20 + pw * 2;
            float m = fmaxf(fmaxf(ap[0], ap[1]), fmaxf(ap[10], ap[11]));
            x2[b * 400 + i] = fmaxf(m, 0.f);
        }
    }
}

// head: fc1 + act4 + logits3 + argmax + rank-based NG loss; block per b, 512 thr (8 waves)
// All global reads wave-coalesced: fc1 = wave-per-output, logits3 = wave-per-key.
__global__ __launch_bounds__(512) void head_kernel(
        const float* __restrict__ x2, const float* __restrict__ w1,
        const float* __restrict__ b1, const float* __restrict__ w2,
        const float* __restrict__ b2, const float* __restrict__ k3s,
        float* __restrict__ outAct4, float* __restrict__ outL3,
        float* __restrict__ outAssign, float* __restrict__ lossb) {
    int b = blockIdx.x, tid = threadIdx.x;
    int lane = tid & 63, wid = tid >> 6;
    __shared__ float xs[400];
    __shared__ float a3r[120], a3p[120];
    __shared__ float sv[512];
    __shared__ float wsum[8], wmv[8];
    __shared__ int wmi[8];
    for (int i = tid; i < 400; i += 512) xs[i] = x2[b * 400 + i];
    __syncthreads();
    // fc1: wave wid computes outputs o = wid + 8*j; lanes split K (coalesced w1 rows)
#pragma unroll
    for (int j = 0; j < 15; ++j) {
        int o = wid + 8 * j;
        const float* wp = w1 + o * 400;
        float s = 0.f;
#pragma unroll
        for (int i = 0; i < 7; ++i) {
            int c = lane + 64 * i;
            if (c < 400) s += wp[c] * xs[c];
        }
#pragma unroll
        for (int off = 32; off > 0; off >>= 1) s += __shfl_down(s, off, 64);
        if (lane == 0) {
            float acc = s + b1[o];
            a3r[o] = acc;
            a3p[o] = fmaxf(acc, 0.f);
        }
    }
    __syncthreads();
    // logits3: wave wid handles keys k = wid*64 + j; lanes split the 120 dims (float2, coalesced)
#pragma unroll 2
    for (int j = 0; j < 64; ++j) {
        int k = wid * 64 + j;
        float s = 0.f;
        if (lane < 60) {
            const float2 kk = reinterpret_cast<const float2*>(k3s + k * 120)[lane];
            const float2 aa = reinterpret_cast<const float2*>(a3r)[lane];
            float d0 = aa.x - kk.x, d1 = aa.y - kk.y;
            s = d0 * d0 + d1 * d1;
        }
#pragma unroll
        for (int off = 32; off > 0; off >>= 1) s += __shfl_down(s, off, 64);
        if (lane == 0) {
            float v = -sqrtf(s);
            sv[k] = v;
            outL3[b * 512 + k] = v;
        }
    }
    if (tid < 10) {                           // fc2 from relu(act3)
        float acc = b2[tid];
        const float* wp = w2 + tid * 120;
#pragma unroll 4
        for (int c = 0; c < 120; ++c) acc += a3p[c] * wp[c];
        outAct4[b * 10 + tid] = acc;
    }
    __syncthreads();
    // rank of this thread's value (ties broken by index) — no sort needed:
    // sum over sorted ranks == sum over per-element ranks (ties share rank slots).
    float v = sv[tid];
    const float4* sv4 = reinterpret_cast<const float4*>(sv);
    int cnt = 0;
#pragma unroll 4
    for (int j4 = 0; j4 < 128; ++j4) {
        float4 o4 = sv4[j4];
        int jb = j4 * 4;
        cnt += (o4.x < v || (o4.x == v && jb < tid)) ? 1 : 0;
        cnt += (o4.y < v || (o4.y == v && jb + 1 < tid)) ? 1 : 0;
        cnt += (o4.z < v || (o4.z == v && jb + 2 < tid)) ? 1 : 0;
        cnt += (o4.w < v || (o4.w == v && jb + 3 < tid)) ? 1 : 0;
    }
    float contrib = v * v * expf(-(float)cnt);
    // per-wave sum + argmax (first occurrence), then cross-wave on thread 0
    float ssum = contrib;
#pragma unroll
    for (int o = 32; o > 0; o >>= 1) ssum += __shfl_down(ssum, o, 64);
    float mv = v; int mi = tid;
#pragma unroll
    for (int o = 32; o > 0; o >>= 1) {
        float ov = __shfl_down(mv, o, 64);
        int oi = __shfl_down(mi, o, 64);
        if (ov > mv || (ov == mv && oi < mi)) { mv = ov; mi = oi; }
    }
    if (lane == 0) { wsum[wid] = ssum; wmv[wid] = mv; wmi[wid] = mi; }
    __syncthreads();
    if (tid == 0) {
        float tot = 0.f;
        float bmv = wmv[0]; int bmi = wmi[0];
#pragma unroll
        for (int w = 0; w < 8; ++w) {
            tot += wsum[w];
            if (wmv[w] > bmv || (wmv[w] == bmv && wmi[w] < bmi)) { bmv = wmv[w]; bmi = wmi[w]; }
        }
        lossb[b] = tot;
        outAssign[b] = (float)bmi;
    }
}

__global__ void final_kernel(const float* __restrict__ loss_b, float* __restrict__ out_loss) {
    __shared__ float r[256];
    int tid = threadIdx.x;
    r[tid] = loss_b[tid];
    __syncthreads();
    for (int s = 128; s > 0; s >>= 1) {
        if (tid < s) r[tid] += r[tid + s];
        __syncthreads();
    }
    if (tid == 0) out_loss[0] = r[0] / 256.f;
}

extern "C" void kernel_launch(void* const* d_in, const int* in_sizes, int n_in,
                              void* d_out, int out_size, void* d_ws, size_t ws_size,
                              hipStream_t stream) {
    const float* inp = (const float*)d_in[0];
    const float* c1w = (const float*)d_in[1];
    const float* c1b = (const float*)d_in[2];
    const float* g1  = (const float*)d_in[3];
    const float* bb1 = (const float*)d_in[4];
    const float* c2w = (const float*)d_in[5];
    const float* c2b = (const float*)d_in[6];
    const float* g2  = (const float*)d_in[7];
    const float* bb2 = (const float*)d_in[8];
    const float* f1w = (const float*)d_in[9];
    const float* f1b = (const float*)d_in[10];
    const float* f2w = (const float*)d_in[11];
    const float* f2b = (const float*)d_in[12];
    const float* k1  = (const float*)d_in[13];
    const float* k2  = (const float*)d_in[14];
    const float* k3  = (const float*)d_in[15];
    float* out = (float*)d_out;

    // Stash raw c1 (1204224 f) and x1 (301056 f) in the logits2 output region
    // (1638400 f) — written only later in stream order, fully overwritten by logits2.
    float* c1raw = out + OFF_L2;               // 1204224
    float* x1    = c1raw + 1204224;            // 301056 (ends at 1505280 < 1638400)

    // workspace layout (floats) — ~523k floats = 2.09 MB
    float* W = (float*)d_ws;
    float* c2raw = W;                  // 409600
    float* x2    = c2raw + 409600;     // 102400
    float* part1 = x2 + 102400;        // 3072
    float* part2 = part1 + 3072;       // 8192
    float* st1   = part2 + 8192;       // 12
    float* st2   = st1 + 12;           // 32
    float* lossb = st2 + 32;           // 256

    conv1_kernel<<<B * 6, 256, 0, stream>>>(inp, c1w, c1b, c1raw, part1);
    stats_kernel<<<6, 256, 0, stream>>>(part1, st1, 6, 1.f / 200704.f);
    logits1_kernel<<<12544, 256, 0, stream>>>(c1raw, st1, g1, bb1, k1, out + OFF_L1, x1);
    conv2_kernel<<<B * 16, 128, 0, stream>>>(x1, c2w, c2b, c2raw, part2);
    stats_kernel<<<16, 256, 0, stream>>>(part2, st2, 16, 1.f / 25600.f);
    logits2_kernel<<<6400, 256, 0, stream>>>(c2raw, st2, g2, bb2, k2, out + OFF_L2, x2);
    head_kernel<<<B, 512, 0, stream>>>(x2, f1w, f1b, f2w, f2b, k3,
                                       out + OFF_ACT4, out + OFF_L3, out + OFF_ASSIGN, lossb);
    final_kernel<<<1, 256, 0, stream>>>(lossb, out + OFF_LOSS);
}

// Round 7
// 117.005 us; speedup vs baseline: 1.2882x; 1.2882x over previous
//
#include <hip/hip_runtime.h>

#define B 256
#define EPSV 1e-5f

// ---------- output offsets (f32 elements) ----------
#define OFF_ASSIGN 0
#define OFF_LOSS   256
#define OFF_ACT4   257
#define OFF_L1     2817
#define OFF_L2     12847873
#define OFF_L3     14486273

__device__ inline void wave_reduce2(float& s, float& q) {
#pragma unroll
    for (int o = 32; o > 0; o >>= 1) {
        s += __shfl_down(s, o, 64);
        q += __shfl_down(q, o, 64);
    }
}

// conv1: [B,3,32,32] -> raw c1 [B,6,28,28] + per-(b,c) sum/sumsq partials
__global__ __launch_bounds__(256) void conv1_kernel(
        const float* __restrict__ inp, const float* __restrict__ w,
        const float* __restrict__ bias, float* __restrict__ c1,
        float* __restrict__ part) {
    int bc = blockIdx.x; int b = bc / 6, c = bc % 6;
    int tid = threadIdx.x;
    __shared__ float ws[75];
    __shared__ float rs[4], rq[4];
    if (tid < 75) ws[tid] = w[c * 75 + tid];
    __syncthreads();
    const float* ip = inp + b * 3072;
    float bs = bias[c];
    float s = 0.f, sq = 0.f;
    for (int hw = tid; hw < 784; hw += 256) {
        int oh = hw / 28, ow = hw % 28;
        float acc = bs;
#pragma unroll
        for (int ic = 0; ic < 3; ++ic) {
            const float* ipc = ip + ic * 1024 + oh * 32 + ow;
            const float* wc = ws + ic * 25;
#pragma unroll
            for (int kh = 0; kh < 5; ++kh)
#pragma unroll
                for (int kw = 0; kw < 5; ++kw)
                    acc += ipc[kh * 32 + kw] * wc[kh * 5 + kw];
        }
        c1[bc * 784 + hw] = acc;
        s += acc; sq += acc * acc;
    }
    wave_reduce2(s, sq);
    if ((tid & 63) == 0) { rs[tid >> 6] = s; rq[tid >> 6] = sq; }
    __syncthreads();
    if (tid == 0) {
        part[bc * 2]     = rs[0] + rs[1] + rs[2] + rs[3];
        part[bc * 2 + 1] = rq[0] + rq[1] + rq[2] + rq[3];
    }
}

// per-channel stats from B partials; grid = C blocks, 256 thr (one per b)
__global__ void stats_kernel(const float* __restrict__ part, float* __restrict__ stats,
                             int C, float invN) {
    int c = blockIdx.x, tid = threadIdx.x;
    float s = part[(tid * C + c) * 2];
    float q = part[(tid * C + c) * 2 + 1];
    wave_reduce2(s, q);
    __shared__ float rs[4], rq[4];
    if ((tid & 63) == 0) { rs[tid >> 6] = s; rq[tid >> 6] = q; }
    __syncthreads();
    if (tid == 0) {
        float S = rs[0] + rs[1] + rs[2] + rs[3];
        float Q = rq[0] + rq[1] + rq[2] + rq[3];
        float m = S * invN;
        float v = Q * invN - m * m;
        stats[c] = m; stats[C + c] = v;
    }
}

// logits1 (+fused BN-relu-pool -> x1 in 1-of-49 blocks)
__global__ __launch_bounds__(256) void logits1_kernel(
        const float* __restrict__ c1, const float* __restrict__ st,
        const float* __restrict__ g, const float* __restrict__ bb,
        const float* __restrict__ k1s, float* __restrict__ outL1,
        float* __restrict__ x1) {
    __shared__ float sk[384];
    __shared__ float ssc[6], ssh[6];
    int tid = threadIdx.x;
    if (tid < 6) {
        float m = st[tid], v = st[6 + tid];
        float sc = g[tid] * rsqrtf(v + EPSV);
        ssc[tid] = sc; ssh[tid] = bb[tid] - m * sc;
    }
    for (int i = tid; i < 384; i += 256) sk[i] = k1s[i];
    __syncthreads();
    int t = blockIdx.x * 256 + tid;          // B*16*784 = 3211264
    int hw = t % 784; int u = t / 784; int kq = u & 15; int b = u >> 4;
    float a[6];
#pragma unroll
    for (int c = 0; c < 6; ++c)
        a[c] = c1[(b * 6 + c) * 784 + hw] * ssc[c] + ssh[c];
    float* op = outL1 + (long)b * 50176 + kq * 3136 + hw;
#pragma unroll
    for (int j = 0; j < 4; ++j) {
        int k = kq * 4 + j;
        float s = 0.f;
#pragma unroll
        for (int c = 0; c < 6; ++c) { float d = a[c] - sk[k * 6 + c]; s += d * d; }
        op[j * 784] = -sqrtf(s);
    }
    // fused BN+relu+pool: first block of each batch writes x1[b]
    if ((blockIdx.x % 49) == 0) {
        int bb2 = blockIdx.x / 49;
        const float* cp = c1 + bb2 * 4704;
        for (int i = tid; i < 1176; i += 256) {
            int c = i / 196, p = i % 196, ph = p / 14, pw = p % 14;
            const float* ap = cp + c * 784 + ph * 56 + pw * 2;
            float sc = ssc[c], sh = ssh[c];
            float v0 = ap[0] * sc + sh, v1 = ap[1] * sc + sh;
            float v2 = ap[28] * sc + sh, v3 = ap[29] * sc + sh;
            x1[bb2 * 1176 + i] = fmaxf(fmaxf(fmaxf(v0, v1), fmaxf(v2, v3)), 0.f);
        }
    }
}

// conv2: x1 [B,6,14,14] -> raw c2 [B,16,10,10] + partials; block=(b,c), 128 thr
__global__ __launch_bounds__(128) void conv2_kernel(
        const float* __restrict__ x1, const float* __restrict__ w,
        const float* __restrict__ bias, float* __restrict__ c2,
        float* __restrict__ part) {
    int bc = blockIdx.x; int b = bc >> 4, c = bc & 15;
    int tid = threadIdx.x;  // 128
    __shared__ float xs[1176];
    __shared__ float ws[150];
    __shared__ float rs[2], rq[2];
    for (int i = tid; i < 1176; i += 128) xs[i] = x1[b * 1176 + i];
    for (int i = tid; i < 150; i += 128) ws[i] = w[c * 150 + i];
    __syncthreads();
    float val = 0.f;
    if (tid < 100) {
        int oh = tid / 10, ow = tid % 10;
        float acc = bias[c];
#pragma unroll
        for (int ic = 0; ic < 6; ++ic) {
            const float* xp = xs + ic * 196 + oh * 14 + ow;
            const float* wp = ws + ic * 25;
#pragma unroll
            for (int kh = 0; kh < 5; ++kh)
#pragma unroll
                for (int kw = 0; kw < 5; ++kw)
                    acc += xp[kh * 14 + kw] * wp[kh * 5 + kw];
        }
        c2[bc * 100 + tid] = acc;
        val = acc;
    }
    float s = val, sq = val * val;
    wave_reduce2(s, sq);
    if ((tid & 63) == 0) { rs[tid >> 6] = s; rq[tid >> 6] = sq; }
    __syncthreads();
    if (tid == 0) {
        part[bc * 2]     = rs[0] + rs[1];
        part[bc * 2 + 1] = rq[0] + rq[1];
    }
}

// logits2 (+fused pool -> x2 in 1-of-25 blocks); act2 staged BN'd in LDS
__global__ __launch_bounds__(256) void logits2_kernel(
        const float* __restrict__ c2, const float* __restrict__ st,
        const float* __restrict__ g, const float* __restrict__ bb,
        const float* __restrict__ k2s, float* __restrict__ outL2,
        float* __restrict__ x2) {
    __shared__ float sk[1024];
    __shared__ float sa[1600];
    __shared__ float ssc[16], ssh[16];
    int tid = threadIdx.x;
    int t0 = blockIdx.x * 256;
    int b = t0 / 6400;                       // constant per block (6400 % 256 == 0)
    if (tid < 16) {
        float m = st[tid], v = st[16 + tid];
        float sc = g[tid] * rsqrtf(v + EPSV);
        ssc[tid] = sc; ssh[tid] = bb[tid] - m * sc;
    }
    for (int i = tid; i < 1024; i += 256) sk[i] = k2s[i];
    __syncthreads();
    for (int i = tid; i < 1600; i += 256) {
        int c = i / 100;
        sa[i] = c2[b * 1600 + i] * ssc[c] + ssh[c];
    }
    __syncthreads();
    int t = t0 + tid;
    int hw = t % 100; int k = (t / 100) & 63;
    float s = 0.f;
#pragma unroll
    for (int c = 0; c < 16; ++c) { float d = sa[c * 100 + hw] - sk[k * 16 + c]; s += d * d; }
    outL2[t] = -sqrtf(s);
    if ((blockIdx.x % 25) == 0) {            // fused relu+pool from BN'd LDS tile
        for (int i = tid; i < 400; i += 256) {
            int c = i / 25, p = i % 25, ph = p / 5, pw = p % 5;
            const float* ap = sa + c * 100 + ph * 20 + pw * 2;
            float m = fmaxf(fmaxf(ap[0], ap[1]), fmaxf(ap[10], ap[11]));
            x2[b * 400 + i] = fmaxf(m, 0.f);
        }
    }
}

// head: fc1 + act4 + logits3 + argmax + rank-based NG loss; block per b, 512 thr.
// NO shuffle chains in inner loops (each __shfl is a ~120cy DS op on CDNA);
// per-thread float4 dots with deep ILP instead.
__global__ __launch_bounds__(512) void head_kernel(
        const float* __restrict__ x2, const float* __restrict__ w1,
        const float* __restrict__ b1, const float* __restrict__ w2,
        const float* __restrict__ b2, const float* __restrict__ k3s,
        float* __restrict__ outAct4, float* __restrict__ outL3,
        float* __restrict__ outAssign, float* __restrict__ lossb) {
    int b = blockIdx.x, tid = threadIdx.x;
    int lane = tid & 63, wid = tid >> 6;
    __shared__ float xs[400];
    __shared__ float a3r[120], a3p[120];
    __shared__ float sv[512];
    __shared__ float wsum[8], wmv[8];
    __shared__ int wmi[8];
    for (int i = tid; i < 400; i += 512) xs[i] = x2[b * 400 + i];
    __syncthreads();
    // fc1: threads 0..239 -> (o = tid>>1, half = tid&1), 200-dim half-dot, 50x float4
    if (tid < 240) {
        int o = tid >> 1, h = tid & 1;
        const float4* wp = reinterpret_cast<const float4*>(w1 + o * 400 + h * 200);
        const float4* xp = reinterpret_cast<const float4*>(xs + h * 200);
        float s = 0.f;
#pragma unroll 10
        for (int c = 0; c < 50; ++c) {
            float4 wv = wp[c], xv = xp[c];
            s += wv.x * xv.x + wv.y * xv.y + wv.z * xv.z + wv.w * xv.w;
        }
        s += __shfl_down(s, 1, 64);          // single DS op, pairs in same wave
        if (h == 0) {
            float acc = s + b1[o];
            a3r[o] = acc;
            a3p[o] = fmaxf(acc, 0.f);
        }
    }
    __syncthreads();
    // logits3: each thread its own key, 30x float4, no reduction
    float v;
    {
        const float4* kp = reinterpret_cast<const float4*>(k3s + tid * 120);
        const float4* ap = reinterpret_cast<const float4*>(a3r);
        float s = 0.f;
#pragma unroll 6
        for (int c = 0; c < 30; ++c) {
            float4 kv = kp[c], av = ap[c];
            float d0 = av.x - kv.x, d1 = av.y - kv.y;
            float d2 = av.z - kv.z, d3 = av.w - kv.w;
            s += d0 * d0 + d1 * d1 + d2 * d2 + d3 * d3;
        }
        v = -sqrtf(s);
        sv[tid] = v;
        outL3[b * 512 + tid] = v;
    }
    if (tid < 10) {                           // fc2 from relu(act3)
        float acc = b2[tid];
        const float* wp = w2 + tid * 120;
#pragma unroll 8
        for (int c = 0; c < 120; ++c) acc += a3p[c] * wp[c];
        outAct4[b * 10 + tid] = acc;
    }
    __syncthreads();
    // rank of this thread's value (ties by index) — equals its sorted position,
    // so sum v^2*exp(-rank) over threads == sum over sorted order.
    const float4* sv4 = reinterpret_cast<const float4*>(sv);
    int cnt = 0;
#pragma unroll 8
    for (int j4 = 0; j4 < 128; ++j4) {
        float4 o4 = sv4[j4];
        int jb = j4 * 4;
        cnt += (o4.x < v || (o4.x == v && jb < tid)) ? 1 : 0;
        cnt += (o4.y < v || (o4.y == v && jb + 1 < tid)) ? 1 : 0;
        cnt += (o4.z < v || (o4.z == v && jb + 2 < tid)) ? 1 : 0;
        cnt += (o4.w < v || (o4.w == v && jb + 3 < tid)) ? 1 : 0;
    }
    float contrib = v * v * expf(-(float)cnt);
    // per-wave sum + argmax (once), then cross-wave on thread 0
    float ssum = contrib;
#pragma unroll
    for (int o = 32; o > 0; o >>= 1) ssum += __shfl_down(ssum, o, 64);
    float mv = v; int mi = tid;
#pragma unroll
    for (int o = 32; o > 0; o >>= 1) {
        float ov = __shfl_down(mv, o, 64);
        int oi = __shfl_down(mi, o, 64);
        if (ov > mv || (ov == mv && oi < mi)) { mv = ov; mi = oi; }
    }
    if (lane == 0) { wsum[wid] = ssum; wmv[wid] = mv; wmi[wid] = mi; }
    __syncthreads();
    if (tid == 0) {
        float tot = 0.f;
        float bmv = wmv[0]; int bmi = wmi[0];
#pragma unroll
        for (int w = 0; w < 8; ++w) {
            tot += wsum[w];
            if (wmv[w] > bmv || (wmv[w] == bmv && wmi[w] < bmi)) { bmv = wmv[w]; bmi = wmi[w]; }
        }
        lossb[b] = tot;
        outAssign[b] = (float)bmi;
    }
}

__global__ void final_kernel(const float* __restrict__ loss_b, float* __restrict__ out_loss) {
    __shared__ float r[256];
    int tid = threadIdx.x;
    r[tid] = loss_b[tid];
    __syncthreads();
    for (int s = 128; s > 0; s >>= 1) {
        if (tid < s) r[tid] += r[tid + s];
        __syncthreads();
    }
    if (tid == 0) out_loss[0] = r[0] / 256.f;
}

extern "C" void kernel_launch(void* const* d_in, const int* in_sizes, int n_in,
                              void* d_out, int out_size, void* d_ws, size_t ws_size,
                              hipStream_t stream) {
    const float* inp = (const float*)d_in[0];
    const float* c1w = (const float*)d_in[1];
    const float* c1b = (const float*)d_in[2];
    const float* g1  = (const float*)d_in[3];
    const float* bb1 = (const float*)d_in[4];
    const float* c2w = (const float*)d_in[5];
    const float* c2b = (const float*)d_in[6];
    const float* g2  = (const float*)d_in[7];
    const float* bb2 = (const float*)d_in[8];
    const float* f1w = (const float*)d_in[9];
    const float* f1b = (const float*)d_in[10];
    const float* f2w = (const float*)d_in[11];
    const float* f2b = (const float*)d_in[12];
    const float* k1  = (const float*)d_in[13];
    const float* k2  = (const float*)d_in[14];
    const float* k3  = (const float*)d_in[15];
    float* out = (float*)d_out;

    // Stash raw c1 (1204224 f) and x1 (301056 f) in the logits2 output region
    // (1638400 f) — written only later in stream order, fully overwritten by logits2.
    float* c1raw = out + OFF_L2;               // 1204224
    float* x1    = c1raw + 1204224;            // 301056 (ends at 1505280 < 1638400)

    // workspace layout (floats) — ~523k floats = 2.09 MB
    float* W = (float*)d_ws;
    float* c2raw = W;                  // 409600
    float* x2    = c2raw + 409600;     // 102400
    float* part1 = x2 + 102400;        // 3072
    float* part2 = part1 + 3072;       // 8192
    float* st1   = part2 + 8192;       // 12
    float* st2   = st1 + 12;           // 32
    float* lossb = st2 + 32;           // 256

    conv1_kernel<<<B * 6, 256, 0, stream>>>(inp, c1w, c1b, c1raw, part1);
    stats_kernel<<<6, 256, 0, stream>>>(part1, st1, 6, 1.f / 200704.f);
    logits1_kernel<<<12544, 256, 0, stream>>>(c1raw, st1, g1, bb1, k1, out + OFF_L1, x1);
    conv2_kernel<<<B * 16, 128, 0, stream>>>(x1, c2w, c2b, c2raw, part2);
    stats_kernel<<<16, 256, 0, stream>>>(part2, st2, 16, 1.f / 25600.f);
    logits2_kernel<<<6400, 256, 0, stream>>>(c2raw, st2, g2, bb2, k2, out + OFF_L2, x2);
    head_kernel<<<B, 512, 0, stream>>>(x2, f1w, f1b, f2w, f2b, k3,
                                       out + OFF_ACT4, out + OFF_L3, out + OFF_ASSIGN, lossb);
    final_kernel<<<1, 256, 0, stream>>>(lossb, out + OFF_LOSS);
}